// Round 6
// baseline (275.240 us; speedup 1.0000x reference)
//
#include <hip/hip_runtime.h>
#include <stdint.h>

#define S_LEN 2048
#define DMODEL 2048
#define NQH 16
#define NKVH 4
#define HDK 128

typedef __bf16 bf16x8 __attribute__((ext_vector_type(8)));
typedef float f32x4 __attribute__((ext_vector_type(4)));
typedef float f32x16 __attribute__((ext_vector_type(16)));

__device__ __forceinline__ void async16(const void* g, void* l) {
  __builtin_amdgcn_global_load_lds((const __attribute__((address_space(1))) void*)g,
                                   (__attribute__((address_space(3))) void*)l,
                                   16, 0, 0);
}

__device__ __forceinline__ f32x4 mfma16(bf16x8 a, bf16x8 b, f32x4 c) {
  return __builtin_amdgcn_mfma_f32_16x16x32_bf16(a, b, c, 0, 0, 0);
}
__device__ __forceinline__ f32x16 mfma32(bf16x8 a, bf16x8 b, f32x16 c) {
  return __builtin_amdgcn_mfma_f32_32x32x16_bf16(a, b, c, 0, 0, 0);
}
__device__ __forceinline__ uint32_t pkbf16(float lo, float hi) {
  uint32_t r;
  asm("v_cvt_pk_bf16_f32 %0, %1, %2" : "=v"(r) : "v"(lo), "v"(hi));
  return r;
}

// ---------------- fused fp32 -> bf16 conversion (all 5 tensors) ----------------
__global__ __launch_bounds__(256) void cvt_all(
    const float* __restrict__ i0, const float* __restrict__ i1,
    const float* __restrict__ i2, const float* __restrict__ i3,
    const float* __restrict__ i4, __bf16* __restrict__ o0,
    __bf16* __restrict__ o1, __bf16* __restrict__ o2, __bf16* __restrict__ o3,
    __bf16* __restrict__ o4) {
  int v = blockIdx.x * 256 + threadIdx.x;  // vec8 index; total 2359296
  const float* in;
  __bf16* out;
  int base;
  if (v < 1048576)      { in = i0; out = o0; base = 0; }
  else if (v < 1572864) { in = i1; out = o1; base = 1048576; }
  else if (v < 1703936) { in = i2; out = o2; base = 1572864; }
  else if (v < 1835008) { in = i3; out = o3; base = 1703936; }
  else                  { in = i4; out = o4; base = 1835008; }
  int i = (v - base) * 8;
  const float4* p = (const float4*)(in + i);
  float4 a = p[0], b = p[1];
  bf16x8 o;
  o[0] = (__bf16)a.x; o[1] = (__bf16)a.y; o[2] = (__bf16)a.z; o[3] = (__bf16)a.w;
  o[4] = (__bf16)b.x; o[5] = (__bf16)b.y; o[6] = (__bf16)b.z; o[7] = (__bf16)b.w;
  *(bf16x8*)(out + i) = o;
}

// ---------------- GEMM: C[m,n] = sum_k A[m,k]*B[n,k], 3-way N-routed ----------------
template <bool F32OUT>
__global__ __launch_bounds__(256) void gemm_bt(const __bf16* __restrict__ A,
                                               const __bf16* __restrict__ B0,
                                               const __bf16* __restrict__ B1,
                                               const __bf16* __restrict__ B2,
                                               void* __restrict__ C0,
                                               void* __restrict__ C1,
                                               void* __restrict__ C2,
                                               int Ntot, int Ns1, int Ns2, int K) {
  int nbn = Ntot >> 7;
  int nwg = gridDim.x;
  int bid = blockIdx.x;
  int bx = (bid & 7) * (nwg >> 3) + (bid >> 3);  // XCD swizzle (nwg % 8 == 0)
  int m0 = (bx / nbn) << 7;
  int n0g = (bx % nbn) << 7;
  const __bf16* B;
  void* C;
  int n0, Nc;
  if (n0g < Ns1)      { B = B0; C = C0; n0 = n0g;       Nc = Ns1; }
  else if (n0g < Ns2) { B = B1; C = C1; n0 = n0g - Ns1; Nc = Ns2 - Ns1; }
  else                { B = B2; C = C2; n0 = n0g - Ns2; Nc = Ntot - Ns2; }

  __shared__ __align__(16) uint8_t As[16384]; // [128][64] bf16, XOR-swizzled
  __shared__ __align__(16) uint8_t Bs[16384];

  int t = threadIdx.x, lane = t & 63, w = t >> 6;
  int wr = w >> 1, wc = w & 1;
  f32x4 acc[4][4] = {};

  for (int k0 = 0; k0 < K; k0 += 64) {
#pragma unroll
    for (int i = 0; i < 4; ++i) {
      int c = (i << 8) + t;
      int row = c >> 3;
      int colb = ((c & 7) << 4) ^ ((row & 7) << 4);
      async16((const uint8_t*)(A + (size_t)(m0 + row) * K + k0) + colb, As + c * 16);
      async16((const uint8_t*)(B + (size_t)(n0 + row) * K + k0) + colb, Bs + c * 16);
    }
    __syncthreads();
#pragma unroll
    for (int ks = 0; ks < 2; ++ks) {
      bf16x8 af[4], bfr[4];
#pragma unroll
      for (int m = 0; m < 4; ++m) {
        int row = wr * 64 + m * 16 + (lane & 15);
        int colb = ((ks << 6) + ((lane >> 4) << 4)) ^ ((row & 7) << 4);
        af[m] = *(const bf16x8*)(As + row * 128 + colb);
      }
#pragma unroll
      for (int n = 0; n < 4; ++n) {
        int row = wc * 64 + n * 16 + (lane & 15);
        int colb = ((ks << 6) + ((lane >> 4) << 4)) ^ ((row & 7) << 4);
        bfr[n] = *(const bf16x8*)(Bs + row * 128 + colb);
      }
      __builtin_amdgcn_s_setprio(1);
#pragma unroll
      for (int m = 0; m < 4; ++m)
#pragma unroll
        for (int n = 0; n < 4; ++n)
          acc[m][n] = mfma16(af[m], bfr[n], acc[m][n]);
      __builtin_amdgcn_s_setprio(0);
    }
    __syncthreads();
  }
#pragma unroll
  for (int m = 0; m < 4; ++m)
#pragma unroll
    for (int n = 0; n < 4; ++n)
#pragma unroll
      for (int j = 0; j < 4; ++j) {
        int mg = m0 + wr * 64 + m * 16 + ((lane >> 4) << 2) + j;
        int ng = n0 + wc * 64 + n * 16 + (lane & 15);
        float v = acc[m][n][j];
        if (F32OUT) ((float*)C)[(size_t)mg * Nc + ng] = v;
        else        ((__bf16*)C)[(size_t)mg * Nc + ng] = (__bf16)v;
      }
}

// ---------------- V transpose: (B*S, 512) -> Vt[(b*4+kvh)*128 + d][s] ----------------
__global__ __launch_bounds__(256) void transpose_v(const __bf16* __restrict__ V,
                                                   __bf16* __restrict__ Vt) {
  int bid = blockIdx.x;
  int dt = bid & 1, st = (bid >> 1) & 31, kvh = (bid >> 6) & 3, b = bid >> 8;
  __shared__ __align__(16) __bf16 tile[64][72];
  int t = threadIdx.x;
#pragma unroll
  for (int i = 0; i < 2; ++i) {
    int c = (i << 8) + t;
    int sr = c >> 3, cb = (c & 7) << 3;
    bf16x8 v = *(const bf16x8*)(V + (size_t)(b * S_LEN + st * 64 + sr) * 512 +
                                kvh * HDK + dt * 64 + cb);
    *(bf16x8*)(&tile[sr][cb]) = v;
  }
  __syncthreads();
#pragma unroll
  for (int i = 0; i < 2; ++i) {
    int c = (i << 8) + t;
    int dr = c >> 3, sb = (c & 7) << 3;
    bf16x8 o;
#pragma unroll
    for (int j = 0; j < 8; ++j) o[j] = tile[sb + j][dr];
    *(bf16x8*)(Vt + (size_t)((b * NKVH + kvh) * HDK + dt * 64 + dr) * S_LEN +
               st * 64 + sb) = o;
  }
}

// ---------------- causal GQA flash attention, 32x32 swapped-QK^T ----------------
// 8 waves: wave-halves split each kv-tile's 64 keys (32 each), independent online
// softmax per half, intra-block flash-merge at epilogue. 4 waves/SIMD occupancy.
__global__ __launch_bounds__(512, 4) void attn(const __bf16* __restrict__ Q,
                                               const __bf16* __restrict__ Kx,
                                               const __bf16* __restrict__ Vt,
                                               __bf16* __restrict__ Ctx) {
  int bid0 = blockIdx.x;
  int bid = ((bid0 & 7) << 6) | (bid0 >> 3);  // XCD swizzle: 512 blocks, 64/XCD
  int qt = 15 - (bid & 15);
  int h = (bid >> 4) & 15;
  int b = bid >> 8;
  int kvh = h >> 2;
  int q0 = qt << 7;
  int t = threadIdx.x, lane = t & 63, w = t >> 6;
  int half = w >> 2, wq = w & 3;
  int qr = lane & 31;   // own q-row within wave
  int hi = lane >> 5;
  int qwb = q0 + (wq << 5);
  int kofs = half << 5;  // this wave's key offset within each kv-tile

  __shared__ __align__(16) uint8_t Ks[2][16384];  // [64 key][128 d] bf16, swizzled
  __shared__ __align__(16) uint8_t Vs[2][16384];  // [128 d][64 key] bf16, swizzled
  __shared__ float MLs[4][2][32];                 // per-wq m,l of half-1 waves

  const __bf16* kbase = Kx + (size_t)b * S_LEN * 512 + kvh * HDK;
  const __bf16* vbase = Vt + (size_t)(b * NKVH + kvh) * HDK * S_LEN;

  auto stage = [&](int kt, int bufi) {
#pragma unroll
    for (int i = 0; i < 2; ++i) {
      int c = (i << 9) + t;
      int krow = c >> 4;
      int kcolb = ((c & 15) << 4) ^ ((krow & 7) << 4);
      async16((const uint8_t*)(kbase + (size_t)((kt << 6) + krow) * 512) + kcolb,
              Ks[bufi] + c * 16);
      int vrow = c >> 3;
      int vcolb = ((c & 7) << 4) ^ ((vrow & 7) << 4);
      async16((const uint8_t*)(vbase + (size_t)vrow * S_LEN + (kt << 6)) + vcolb,
              Vs[bufi] + c * 16);
    }
  };

  int NT = (qt << 1) + 2;
  stage(0, 0);

  // Q fragments: lane holds Q[q = qwb+qr][d = dk*16 + hi*8 + j]
  bf16x8 qf[8];
  {
    const __bf16* qrow = Q + (size_t)(b * S_LEN + qwb + qr) * DMODEL + h * HDK + hi * 8;
#pragma unroll
    for (int dk = 0; dk < 8; ++dk) qf[dk] = *(const bf16x8*)(qrow + dk * 16);
  }
  __syncthreads();

  const float NEG = -3.0e38f;
  const float SC = 0.08838834764831845f;  // 1/sqrt(128)
  float m_run = NEG, l_run = 0.f;
  f32x16 acc[4] = {};  // O[q(regs)][d(lanes)], 4 d-tiles of 32

  for (int kt = 0; kt < NT; ++kt) {
    int cur = kt & 1;
    if (kt + 1 < NT) stage(kt + 1, cur ^ 1);
    int k0 = kt << 6;
    if (k0 + kofs <= qwb + 31) {  // wave-uniform skip of fully-masked half-tiles
      const uint8_t* ks = Ks[cur];
      const uint8_t* vs = Vs[cur];

      // S^T = K Q^T : D[key][q], col=q=lane&31, row=(r&3)+8*(r>>2)+4*hi
      f32x16 st = {};
      int swz = (qr & 7) << 4;
      __builtin_amdgcn_s_setprio(1);
#pragma unroll
      for (int dk = 0; dk < 8; ++dk) {
        bf16x8 kf = *(const bf16x8*)(ks + (kofs + qr) * 256 +
                                     (((dk << 5) + (hi << 4)) ^ swz));
        st = mfma32(kf, qf[dk], st);
      }
      __builtin_amdgcn_s_setprio(0);

      // causal mask (diagonal-adjacent half-tiles only)
      if (k0 + kofs + 31 > qwb) {
#pragma unroll
        for (int r = 0; r < 16; ++r) {
          int kl = (r & 3) + ((r >> 2) << 3) + (hi << 2);
          st[r] = (k0 + kofs + kl > qwb + qr) ? NEG : st[r];
        }
      }

      // row max: binary tree (depth 4) + one cross-hi merge
      float tm[8];
#pragma unroll
      for (int r = 0; r < 8; ++r) tm[r] = fmaxf(st[r], st[r + 8]);
#pragma unroll
      for (int s = 4; s > 0; s >>= 1)
#pragma unroll
        for (int r = 0; r < s; ++r) tm[r] = fmaxf(tm[r], tm[r + s]);
      float mx = fmaxf(tm[0], __shfl_xor(tm[0], 32, 64));

      // defer-max: rescale only when max grows by >8/SC in raw score units
      if (__any(mx > m_run + 90.52f)) {
        float mn = fmaxf(m_run, mx);
        float al = __expf((m_run - mn) * SC);
        l_run *= al;
        m_run = mn;
#pragma unroll
        for (int i = 0; i < 16; ++i) {
          float alr = __shfl(al, (i & 3) + ((i >> 2) << 3) + (hi << 2), 64);
          acc[0][i] *= alr; acc[1][i] *= alr; acc[2][i] *= alr; acc[3][i] *= alr;
        }
      }

      float mSC = m_run * SC;
      float p0[16];
#pragma unroll
      for (int r = 0; r < 16; ++r) p0[r] = __expf(fmaf(st[r], SC, -mSC));
      // row sum: binary tree + one cross-hi merge
      float ts[8];
#pragma unroll
      for (int r = 0; r < 8; ++r) ts[r] = p0[r] + p0[r + 8];
#pragma unroll
      for (int s = 4; s > 0; s >>= 1)
#pragma unroll
        for (int r = 0; r < s; ++r) ts[r] += ts[r + s];
      l_run += ts[0] + __shfl_xor(ts[0], 32, 64);

      // pack P to bf16 and redistribute to PV A-frag layout (shfl_xor + select)
      uint32_t wd0[4][2];
#pragma unroll
      for (int g = 0; g < 4; ++g) {
        wd0[g][0] = pkbf16(p0[4 * g + 0], p0[4 * g + 1]);
        wd0[g][1] = pkbf16(p0[4 * g + 2], p0[4 * g + 3]);
      }
      bf16x8 pa[2];
      {
        uint32_t s0 = hi ? wd0[0][0] : wd0[1][0];
        uint32_t s1 = hi ? wd0[0][1] : wd0[1][1];
        uint32_t s2 = hi ? wd0[2][0] : wd0[3][0];
        uint32_t s3 = hi ? wd0[2][1] : wd0[3][1];
        uint32_t r0 = (uint32_t)__shfl_xor((int)s0, 32, 64);
        uint32_t r1 = (uint32_t)__shfl_xor((int)s1, 32, 64);
        uint32_t r2 = (uint32_t)__shfl_xor((int)s2, 32, 64);
        uint32_t r3 = (uint32_t)__shfl_xor((int)s3, 32, 64);
        union { bf16x8 v; uint32_t u[4]; } fa, fb;
        fa.u[0] = hi ? r0 : wd0[0][0];
        fa.u[1] = hi ? r1 : wd0[0][1];
        fa.u[2] = hi ? wd0[1][0] : r0;
        fa.u[3] = hi ? wd0[1][1] : r1;
        fb.u[0] = hi ? r2 : wd0[2][0];
        fb.u[1] = hi ? r3 : wd0[2][1];
        fb.u[2] = hi ? wd0[3][0] : r2;
        fb.u[3] = hi ? wd0[3][1] : r3;
        pa[0] = fa.v;
        pa[1] = fb.v;
      }

      // O += P V : A=pa (P[q][k]), B=V[k][d] from d-major Vt_lds
      __builtin_amdgcn_s_setprio(1);
#pragma unroll
      for (int dt = 0; dt < 4; ++dt) {
        int row = (dt << 5) + qr;
        int swzv = (row & 7) << 4;
#pragma unroll
        for (int kc = 0; kc < 2; ++kc) {
          bf16x8 vf = *(const bf16x8*)(
              vs + row * 128 + (((kofs << 1) + (kc << 5) + (hi << 4)) ^ swzv));
          acc[dt] = mfma32(pa[kc], vf, acc[dt]);
        }
      }
      __builtin_amdgcn_s_setprio(0);
    }
    __syncthreads();
  }

  // ---- intra-block flash-merge of the two key-halves (K/V LDS is dead now) ----
  float* obuf = (wq < 2) ? (float*)(&Ks[0][0] + wq * 16384)
                         : (float*)(&Vs[0][0] + (wq - 2) * 16384);
  if (half) {
    if (hi == 0) { MLs[wq][0][qr] = m_run; MLs[wq][1][qr] = l_run; }
#pragma unroll
    for (int dt = 0; dt < 4; ++dt)
#pragma unroll
      for (int i4 = 0; i4 < 4; ++i4) {
        f32x4 v4 = {acc[dt][i4 * 4 + 0], acc[dt][i4 * 4 + 1],
                    acc[dt][i4 * 4 + 2], acc[dt][i4 * 4 + 3]};
        *(f32x4*)(obuf + dt * 1024 + lane * 16 + i4 * 4) = v4;
      }
  }
  __syncthreads();
  if (!half) {
    float m1 = MLs[wq][0][qr], l1 = MLs[wq][1][qr];
    float ms = fmaxf(m_run, m1);
    float a0 = __expf((m_run - ms) * SC);
    float a1 = __expf((m1 - ms) * SC);
    float linv = 1.f / (l_run * a0 + l1 * a1);
#pragma unroll
    for (int i = 0; i < 16; ++i) {
      int rm = (i & 3) + ((i >> 2) << 3) + (hi << 2);
      float a0r = __shfl(a0, rm, 64);
      float a1r = __shfl(a1, rm, 64);
      float invr = __shfl(linv, rm, 64);
      size_t rowoff = (size_t)(b * S_LEN + qwb + rm) * DMODEL + h * HDK + qr;
#pragma unroll
      for (int dt = 0; dt < 4; ++dt) {
        float o1 = obuf[dt * 1024 + lane * 16 + i];
        Ctx[rowoff + (dt << 5)] =
            (__bf16)((acc[dt][i] * a0r + o1 * a1r) * invr);
      }
    }
  }
}

// ---------------- launch ----------------
extern "C" void kernel_launch(void* const* d_in, const int* in_sizes, int n_in,
                              void* d_out, int out_size, void* d_ws, size_t ws_size,
                              hipStream_t stream) {
  const float* x  = (const float*)d_in[0];
  const float* Wq = (const float*)d_in[1];
  const float* Wk = (const float*)d_in[2];
  const float* Wv = (const float*)d_in[3];
  const float* Wo = (const float*)d_in[4];
  float* out = (float*)d_out;

  const size_t MB = 1024 * 1024;
  uint8_t* ws = (uint8_t*)d_ws;
  __bf16* xb  = (__bf16*)(ws + 0 * MB);   // 16 MB  (4096 x 2048)
  __bf16* Wqb = (__bf16*)(ws + 16 * MB);  //  8 MB  (2048 x 2048)
  __bf16* Wkb = (__bf16*)(ws + 24 * MB);  //  2 MB  (512 x 2048)
  __bf16* Wvb = (__bf16*)(ws + 26 * MB);  //  2 MB
  __bf16* Wob = (__bf16*)(ws + 28 * MB);  //  8 MB
  __bf16* Qb  = (__bf16*)(ws + 36 * MB);  // 16 MB  (4096 x 2048)
  __bf16* Kb  = (__bf16*)(ws + 52 * MB);  //  4 MB  (4096 x 512)
  __bf16* Vb  = (__bf16*)(ws + 56 * MB);  //  4 MB
  __bf16* Vtb = (__bf16*)(ws + 60 * MB);  //  4 MB  (1024 x 2048)
  __bf16* Ctx = (__bf16*)(ws + 64 * MB);  // 16 MB  (4096 x 2048)

  // fused conversion: 18.9M elems / 8 per thread / 256 per block = 9216 blocks
  cvt_all<<<9216, 256, 0, stream>>>(x, Wq, Wk, Wv, Wo, xb, Wqb, Wkb, Wvb, Wob);

  // fused QKV projection: (4096x2048) x [Wq;Wk;Wv]^T, N = 2048+512+512
  gemm_bt<false><<<(4096 / 128) * (3072 / 128), 256, 0, stream>>>(
      xb, Wqb, Wkb, Wvb, (void*)Qb, (void*)Kb, (void*)Vb, 3072, 2048, 2560, 2048);

  transpose_v<<<512, 256, 0, stream>>>(Vb, Vtb);

  attn<<<512, 512, 0, stream>>>(Qb, Kb, Vtb, Ctx);

  // output projection: (4096x2048) x (2048x2048)^T -> fp32
  gemm_bt<true><<<(4096 / 128) * (2048 / 128), 256, 0, stream>>>(
      Ctx, Wob, Wob, Wob, (void*)out, (void*)out, (void*)out, 2048, 2048, 2048, 2048);
}